// Round 1
// 1245.195 us; speedup vs baseline: 1.0409x; 1.0409x over previous
//
#include <hip/hip_runtime.h>
#include <math.h>

#define NROWS 8192
#define NCOLS 32000
#define BLOCK 256

// 32000 floats / 4 = 8000 float4 per row = 31 full block-iterations (7936) + 64 tail
#define VEC_PER_ROW (NCOLS / 4)     // 8000
#define FULL_ITERS 31               // 31 * 256 = 7936
#define TAIL_BASE (FULL_ITERS * BLOCK)  // 7936, 64 remaining

typedef float f32x4 __attribute__((ext_vector_type(4)));

__device__ __forceinline__ float wave_reduce_sum(float v) {
    #pragma unroll
    for (int off = 32; off > 0; off >>= 1)
        v += __shfl_down(v, off, 64);
    return v;
}

// Constants for ArcFace with M = 0.5, S = 30
// cos(M)  = 0.8775825618903728
// sin(M)  = 0.4794255386042030
// MM      = sin(pi - M)*M = sin(M)*M = 0.2397127693021015
// THRESH  = cos(pi - M)   = -cos(M)  = -0.8775825618903728
#define COS_M 0.8775825618903728f
#define SIN_M 0.4794255386042030f
#define MM_C 0.2397127693021015f
#define THRESH_C (-0.8775825618903728f)
#define SCALE_S 30.0f

__device__ __forceinline__ float clamp_exp_sum4(f32x4 v) {
    float a = fminf(fmaxf(v.x, -1.0f), 1.0f);
    float b = fminf(fmaxf(v.y, -1.0f), 1.0f);
    float c = fminf(fmaxf(v.z, -1.0f), 1.0f);
    float d = fminf(fmaxf(v.w, -1.0f), 1.0f);
    return (__expf(SCALE_S * a) + __expf(SCALE_S * b)) +
           (__expf(SCALE_S * c) + __expf(SCALE_S * d));
}

__global__ __launch_bounds__(BLOCK, 8) void arcface_row_kernel(
    const float* __restrict__ pred,
    const int* __restrict__ target,
    float* __restrict__ row_loss)
{
    const int row = blockIdx.x;
    const int tid = threadIdx.x;
    const f32x4* __restrict__ p4 = (const f32x4*)(pred + (size_t)row * NCOLS);

    // Hoist the target-column load so its latency hides under the main loop.
    int t = 0;
    float x = 0.0f;
    if (tid == 0) {
        t = target[row];
        x = pred[(size_t)row * NCOLS + t];
    }

    // 4 independent accumulators + 4 independent nontemporal dwordx4 loads
    // in flight per thread -> 4x the memory-level parallelism of the old
    // single-buffer dynamic-trip loop. Static trip counts let the compiler
    // fully pipeline; nt loads skip L2 (zero reuse).
    float s0 = 0.0f, s1 = 0.0f, s2 = 0.0f, s3 = 0.0f;

    for (int i = 0; i < 28; i += 4) {
        f32x4 v0 = __builtin_nontemporal_load(p4 + (i + 0) * BLOCK + tid);
        f32x4 v1 = __builtin_nontemporal_load(p4 + (i + 1) * BLOCK + tid);
        f32x4 v2 = __builtin_nontemporal_load(p4 + (i + 2) * BLOCK + tid);
        f32x4 v3 = __builtin_nontemporal_load(p4 + (i + 3) * BLOCK + tid);
        s0 += clamp_exp_sum4(v0);
        s1 += clamp_exp_sum4(v1);
        s2 += clamp_exp_sum4(v2);
        s3 += clamp_exp_sum4(v3);
    }
    {   // iterations 28, 29, 30
        f32x4 v0 = __builtin_nontemporal_load(p4 + 28 * BLOCK + tid);
        f32x4 v1 = __builtin_nontemporal_load(p4 + 29 * BLOCK + tid);
        f32x4 v2 = __builtin_nontemporal_load(p4 + 30 * BLOCK + tid);
        s0 += clamp_exp_sum4(v0);
        s1 += clamp_exp_sum4(v1);
        s2 += clamp_exp_sum4(v2);
    }
    if (tid < (VEC_PER_ROW - TAIL_BASE)) {   // 64-thread tail: indices 7936..7999
        f32x4 v = __builtin_nontemporal_load(p4 + TAIL_BASE + tid);
        s3 += clamp_exp_sum4(v);
    }

    float sum = (s0 + s1) + (s2 + s3);

    // block reduction: 4 waves of 64
    __shared__ float smem[BLOCK / 64];
    float wsum = wave_reduce_sum(sum);
    const int lane = tid & 63;
    const int wid = tid >> 6;
    if (lane == 0) smem[wid] = wsum;
    __syncthreads();

    if (tid == 0) {
        float total = smem[0] + smem[1] + smem[2] + smem[3];
        x = fminf(fmaxf(x, -1.0f), 1.0f);
        // cos(arccos(x) + M) = x*cos(M) - sqrt(1-x^2)*sin(M)
        float tm;
        if (x > THRESH_C) {
            tm = x * COS_M - sqrtf(fmaxf(1.0f - x * x, 0.0f)) * SIN_M;
        } else {
            tm = x - MM_C;
        }
        // replace target column's contribution
        total = total - __expf(SCALE_S * x) + __expf(SCALE_S * tm);
        row_loss[row] = __logf(total) - SCALE_S * tm;
    }
}

__global__ __launch_bounds__(BLOCK) void arcface_final_kernel(
    const float* __restrict__ row_loss,
    float* __restrict__ out)
{
    const int tid = threadIdx.x;
    float sum = 0.0f;
    for (int i = tid; i < NROWS; i += BLOCK) sum += row_loss[i];

    __shared__ float smem[BLOCK / 64];
    float wsum = wave_reduce_sum(sum);
    const int lane = tid & 63;
    const int wid = tid >> 6;
    if (lane == 0) smem[wid] = wsum;
    __syncthreads();
    if (tid == 0) {
        float total = smem[0] + smem[1] + smem[2] + smem[3];
        out[0] = total / (float)NROWS;   // LOSS_WEIGHT = 1.0
    }
}

extern "C" void kernel_launch(void* const* d_in, const int* in_sizes, int n_in,
                              void* d_out, int out_size, void* d_ws, size_t ws_size,
                              hipStream_t stream) {
    const float* pred = (const float*)d_in[0];
    const int* target = (const int*)d_in[1];
    float* out = (float*)d_out;
    float* row_loss = (float*)d_ws;   // NROWS floats = 32 KB scratch

    arcface_row_kernel<<<NROWS, BLOCK, 0, stream>>>(pred, target, row_loss);
    arcface_final_kernel<<<1, BLOCK, 0, stream>>>(row_loss, out);
}